// Round 5
// baseline (205.300 us; speedup 1.0000x reference)
//
#include <hip/hip_runtime.h>
#include <stdint.h>

#define B_ 4
#define L_ 4096
#define D_ 1024
#define C_ 2048
#define M_ (B_ * L_)  // 16384

typedef __attribute__((ext_vector_type(8))) short s16x8;
typedef __attribute__((ext_vector_type(4))) float fx4;
typedef unsigned short bfu;  // bf16 bits

__device__ __forceinline__ float bits2f(short s) {
  return __uint_as_float(((uint32_t)(unsigned short)s) << 16);
}
__device__ __forceinline__ bfu f2bf(float f) {
  uint32_t u = __float_as_uint(f);
  uint32_t r = (u + 0x7FFFu + ((u >> 16) & 1u)) >> 16;  // RNE
  return (bfu)r;
}

__device__ __forceinline__ void gload_lds16(const void* g, void* l) {
  __builtin_amdgcn_global_load_lds(
      (const __attribute__((address_space(1))) void*)g,
      (__attribute__((address_space(3))) void*)l, 16, 0, 0);
}

#define BAR() asm volatile("s_barrier" ::: "memory")
#define LGKM0() asm volatile("s_waitcnt lgkmcnt(0)" ::: "memory")
#define VMW4() asm volatile("s_waitcnt vmcnt(4)" ::: "memory")
#define VMW0() asm volatile("s_waitcnt vmcnt(0)" ::: "memory")

// ---------------- fp32 -> bf16 bulk convert ----------------
__global__ __launch_bounds__(256) void cvt_f32_bf16(const float* __restrict__ in,
                                                    bfu* __restrict__ out, int n8) {
  const int stride = gridDim.x * blockDim.x;
  for (int i = blockIdx.x * blockDim.x + threadIdx.x; i < n8; i += stride) {
    const size_t off = (size_t)i * 8;
    fx4 a = *(const fx4*)(in + off);
    fx4 b = *(const fx4*)(in + off + 4);
    s16x8 o;
#pragma unroll
    for (int j = 0; j < 4; j++) {
      o[j] = (short)f2bf(a[j]);
      o[j + 4] = (short)f2bf(b[j]);
    }
    *reinterpret_cast<s16x8*>(out + off) = o;
  }
}

// ---------------- transpose + fp32->bf16 convert: out[c][r] = in[r][c] ----------------
template <int R, int CC>
__global__ __launch_bounds__(256) void transpose_cvt(const float* __restrict__ in,
                                                     bfu* __restrict__ out) {
  __shared__ float tile[32][33];
  const int bx = blockIdx.x, by = blockIdx.y, tx = threadIdx.x;
  for (int j = threadIdx.y; j < 32; j += 8)
    tile[j][tx] = in[(size_t)(by * 32 + j) * CC + bx * 32 + tx];
  __syncthreads();
  for (int j = threadIdx.y; j < 32; j += 8)
    out[(size_t)(bx * 32 + j) * R + by * 32 + tx] = f2bf(tile[tx][j]);
}

// ---------------- boundary A pack: A_bnd[16i+k] = xb[256i-3+k], i=1..63, k=0..2 -------
__global__ __launch_bounds__(128) void bnd_pack(const bfu* __restrict__ xb,
                                                bfu* __restrict__ A_bnd) {
  const int i = blockIdx.x / 3 + 1;
  const int k = blockIdx.x % 3;
  const int t = threadIdx.x;
  *reinterpret_cast<s16x8*>(A_bnd + (size_t)(i * 16 + k) * D_ + t * 8) =
      *reinterpret_cast<const s16x8*>(xb + (size_t)(i * 256 - 3 + k) * D_ + t * 8);
}

// =================== 256x256 8-phase GEMM core pieces ===================
// LDS buffer (per dbuf half, elements): A-kh0 @0, A-kh1 @8192, B-kh0 @16384,
// B-kh1 @24576; buf1 = +32768.  Rows are 64 B.  Swizzle involution:
// slot' = slot ^ ((row>>1)&3)  <=>  byte ^= ((byte>>3)&48).

template <int KD>
__device__ __forceinline__ void stage_half(const bfu* __restrict__ Mt, int r0, int kb,
                                           bfu* region, int t) {
#pragma unroll
  for (int h = 0; h < 2; h++) {
    const int u = t + h * 512;
    const int srow = u >> 2;
    const int sslot = (u & 3) ^ ((srow >> 1) & 3);
    gload_lds16(Mt + (size_t)(r0 + srow) * KD + kb + sslot * 8, region + u * 8);
  }
}

#define LF(bytoff) \
  (*reinterpret_cast<const s16x8*>(reinterpret_cast<const char*>(lds) + (bytoff)))

// The full K-loop as a macro-like inline: kept identical between gemm256 and the
// fused kernel. acc[8][4] accumulates; A rows row0.., Bt rows col0..
#define GEMM_KLOOP(A, Bt, KD)                                                          \
  stage_half<KD>(A, row0, 0, lds + 0, t);                                              \
  stage_half<KD>(Bt, col0, 0, lds + 16384, t);                                         \
  stage_half<KD>(A, row0, 32, lds + 8192, t);                                          \
  stage_half<KD>(Bt, col0, 32, lds + 24576, t);                                        \
  stage_half<KD>(A, row0, 64, lds + 32768 + 0, t);                                     \
  stage_half<KD>(Bt, col0, 64, lds + 32768 + 16384, t);                                \
  VMW4();                                                                              \
  BAR();                                                                               \
  for (int tau = 0; tau < ntk; ++tau) {                                                \
    const int cbb = (tau & 1) ? 65536 : 0;                                             \
    bfu* nb_ = (tau & 1) ? lds : lds + 32768;                                          \
    s16x8 af[4], bf4[4];                                                               \
    _Pragma("unroll") for (int m = 0; m < 4; m++) af[m] = LF(cbb + abase + m * 1024);  \
    _Pragma("unroll") for (int n = 0; n < 4; n++) bf4[n] =                             \
        LF(cbb + 32768 + bbase + n * 1024);                                            \
    if (tau + 1 < ntk) stage_half<KD>(A, row0, (tau + 1) * 64 + 32, nb_ + 8192, t);    \
    BAR();                                                                             \
    LGKM0();                                                                           \
    __builtin_amdgcn_s_setprio(1);                                                     \
    _Pragma("unroll") for (int m = 0; m < 4; m++) _Pragma("unroll")                    \
        for (int n = 0; n < 4; n++) acc[m][n] =                                        \
            __builtin_amdgcn_mfma_f32_16x16x32_bf16(af[m], bf4[n], acc[m][n], 0, 0, 0);\
    __builtin_amdgcn_s_setprio(0);                                                     \
    BAR();                                                                             \
    _Pragma("unroll") for (int m = 0; m < 4; m++) af[m] =                              \
        LF(cbb + abase + 4096 + m * 1024);                                             \
    if (tau + 1 < ntk) stage_half<KD>(Bt, col0, (tau + 1) * 64 + 32, nb_ + 24576, t);  \
    BAR();                                                                             \
    LGKM0();                                                                           \
    __builtin_amdgcn_s_setprio(1);                                                     \
    _Pragma("unroll") for (int m = 0; m < 4; m++) _Pragma("unroll")                    \
        for (int n = 0; n < 4; n++) acc[m + 4][n] =                                    \
            __builtin_amdgcn_mfma_f32_16x16x32_bf16(af[m], bf4[n], acc[m + 4][n], 0, 0, 0);\
    __builtin_amdgcn_s_setprio(0);                                                     \
    BAR();                                                                             \
    _Pragma("unroll") for (int m = 0; m < 4; m++) af[m] =                              \
        LF(cbb + 16384 + abase + m * 1024);                                            \
    _Pragma("unroll") for (int n = 0; n < 4; n++) bf4[n] =                             \
        LF(cbb + 49152 + bbase + n * 1024);                                            \
    if (tau + 2 < ntk) stage_half<KD>(A, row0, (tau + 2) * 64, lds + (cbb >> 1), t);   \
    BAR();                                                                             \
    LGKM0();                                                                           \
    __builtin_amdgcn_s_setprio(1);                                                     \
    _Pragma("unroll") for (int m = 0; m < 4; m++) _Pragma("unroll")                    \
        for (int n = 0; n < 4; n++) acc[m][n] =                                        \
            __builtin_amdgcn_mfma_f32_16x16x32_bf16(af[m], bf4[n], acc[m][n], 0, 0, 0);\
    __builtin_amdgcn_s_setprio(0);                                                     \
    BAR();                                                                             \
    _Pragma("unroll") for (int m = 0; m < 4; m++) af[m] =                              \
        LF(cbb + 16384 + abase + 4096 + m * 1024);                                     \
    if (tau + 2 < ntk) stage_half<KD>(Bt, col0, (tau + 2) * 64, lds + (cbb >> 1) + 16384, t);\
    BAR();                                                                             \
    LGKM0();                                                                           \
    __builtin_amdgcn_s_setprio(1);                                                     \
    _Pragma("unroll") for (int m = 0; m < 4; m++) _Pragma("unroll")                    \
        for (int n = 0; n < 4; n++) acc[m + 4][n] =                                    \
            __builtin_amdgcn_mfma_f32_16x16x32_bf16(af[m], bf4[n], acc[m + 4][n], 0, 0, 0);\
    __builtin_amdgcn_s_setprio(0);                                                     \
    if (tau < ntk - 1) {                                                               \
      if (tau < ntk - 2) VMW4();                                                       \
      else VMW0();                                                                     \
    }                                                                                  \
    BAR();                                                                             \
  }

// ---------------- plain 256x256 GEMM (used for boundary GEMM and GEMM2) --------------
template <int MM, int N, int KD, bool OUT_BF16, bool ZERO3>
__global__ __launch_bounds__(512, 2) void gemm256(const bfu* __restrict__ A,
                                                  const bfu* __restrict__ Bt,
                                                  const float* __restrict__ bias,
                                                  void* __restrict__ Cptr) {
  __shared__ bfu lds[2 * 4 * 8192];  // 128 KiB
  const int t = threadIdx.x;
  const int lane = t & 63, wid = t >> 6;
  const int wr = wid >> 2, wc = wid & 3;
  const int lr = lane & 15, lg = lane >> 4;
  const int cpx = gridDim.x >> 3;
  const int li = (blockIdx.x & 7) * cpx + (blockIdx.x >> 3);
  const int row0 = (li % (MM / 256)) * 256;
  const int col0 = (li / (MM / 256)) * 256;
  constexpr int ntk = KD / 64;
  const int abase = ((wr * 128 + lr) * 64 + lg * 16) ^ (((lr >> 1) & 3) << 4);
  const int bbase = ((wc * 64 + lr) * 64 + lg * 16) ^ (((lr >> 1) & 3) << 4);

  fx4 acc[8][4] = {};
  GEMM_KLOOP(A, Bt, KD)

  float bv[4];
#pragma unroll
  for (int n = 0; n < 4; n++) bv[n] = bias[col0 + wc * 64 + n * 16 + lr];
#pragma unroll
  for (int m = 0; m < 8; m++)
#pragma unroll
    for (int n = 0; n < 4; n++)
#pragma unroll
      for (int r = 0; r < 4; r++) {
        const int row = row0 + wr * 128 + m * 16 + lg * 4 + r;
        const int col = col0 + wc * 64 + n * 16 + lr;
        float v = acc[m][n][r] + bv[n];
        if constexpr (ZERO3) {
          if ((row & 255) < 3) v = 0.0f;
        }
        if constexpr (OUT_BF16)
          ((bfu*)Cptr)[(size_t)row * N + col] = f2bf(v);
        else
          ((float*)Cptr)[(size_t)row * N + col] = v;
      }
}

// ---------------- fused GEMM1 + depthwise causal conv ----------------
// y[row] = cb + sum_{tt=0..3} cw[tt] * xe[row-3+tt], xe = x@W_exp + b_exp.
// Boundary xe rows (row0-3..row0-1) come from xe_bnd (zeros at batch starts).
#define XPITCH 264
__global__ __launch_bounds__(512, 2) void gemm_exp_conv(
    const bfu* __restrict__ A, const bfu* __restrict__ Bt,
    const float* __restrict__ bexp, const float* __restrict__ cw,
    const float* __restrict__ cbv, const bfu* __restrict__ xe_bnd,
    bfu* __restrict__ Y) {
  __shared__ bfu lds[68376];  // max(128KB K-loop, [259][264] conv buf) = 136752 B
  const int t = threadIdx.x;
  const int lane = t & 63, wid = t >> 6;
  const int wr = wid >> 2, wc = wid & 3;
  const int lr = lane & 15, lg = lane >> 4;
  const int cpx = gridDim.x >> 3;
  const int li = (blockIdx.x & 7) * cpx + (blockIdx.x >> 3);
  const int row0 = (li % (M_ / 256)) * 256;
  const int col0 = (li / (M_ / 256)) * 256;
  constexpr int ntk = D_ / 64;
  const int abase = ((wr * 128 + lr) * 64 + lg * 16) ^ (((lr >> 1) & 3) << 4);
  const int bbase = ((wc * 64 + lr) * 64 + lg * 16) ^ (((lr >> 1) & 3) << 4);

  fx4 acc[8][4] = {};
  GEMM_KLOOP(A, Bt, D_)

  // ---- epilogue: conv via LDS round-trip (LDS is dead now) ----
  // load conv weights for this thread's 4 columns
  float wv[4][4], cb4[4], bv[4];
#pragma unroll
  for (int n = 0; n < 4; n++) {
    const int col = col0 + wc * 64 + n * 16 + lr;
    bv[n] = bexp[col];
    cb4[n] = cbv[col];
#pragma unroll
    for (int tt = 0; tt < 4; tt++) wv[tt][n] = cw[tt * C_ + col];
  }
  // boundary rows -> Xe[0..2]
  if (t < 96) {
    const int k = t >> 5, seg = t & 31;
    *reinterpret_cast<s16x8*>(lds + k * XPITCH + seg * 8) =
        *reinterpret_cast<const s16x8*>(xe_bnd +
                                        (size_t)((row0 >> 4) + k) * C_ + col0 + seg * 8);
  }
  // main tile -> Xe[3+rl][cl]
#pragma unroll
  for (int m = 0; m < 8; m++)
#pragma unroll
    for (int n = 0; n < 4; n++)
#pragma unroll
      for (int r = 0; r < 4; r++) {
        const int rl = wr * 128 + m * 16 + lg * 4 + r;
        const int cl = wc * 64 + n * 16 + lr;
        lds[(3 + rl) * XPITCH + cl] = f2bf(acc[m][n][r] + bv[n]);
      }
  __syncthreads();
  // conv + store
#pragma unroll
  for (int m = 0; m < 8; m++)
#pragma unroll
    for (int n = 0; n < 4; n++)
#pragma unroll
      for (int r = 0; r < 4; r++) {
        const int rl = wr * 128 + m * 16 + lg * 4 + r;
        const int cl = wc * 64 + n * 16 + lr;
        float v = cb4[n];
#pragma unroll
        for (int tt = 0; tt < 4; tt++)
          v = fmaf(bits2f((short)lds[(rl + tt) * XPITCH + cl]), wv[tt][n], v);
        Y[(size_t)(row0 + rl) * C_ + col0 + cl] = f2bf(v);
      }
}

extern "C" void kernel_launch(void* const* d_in, const int* in_sizes, int n_in,
                              void* d_out, int out_size, void* d_ws, size_t ws_size,
                              hipStream_t stream) {
  const float* x = (const float*)d_in[0];
  const float* W_exp = (const float*)d_in[1];
  const float* b_exp = (const float*)d_in[2];
  const float* cw = (const float*)d_in[3];
  const float* cb = (const float*)d_in[4];
  const float* W_cmp = (const float*)d_in[5];
  const float* b_cmp = (const float*)d_in[6];
  float* out = (float*)d_out;

  char* ws = (char*)d_ws;
  bfu* wexp_t = (bfu*)(ws);                 // [C][D] bf16, 4 MiB
  bfu* wcmp_t = (bfu*)(ws + (4u << 20));    // [D][C] bf16, 4 MiB
  bfu* xb = (bfu*)(ws + (8u << 20));        // [M][D] bf16, 32 MiB
  bfu* A_bnd = (bfu*)(ws + (40u << 20));    // [1024][D] bf16, 2 MiB
  bfu* xe_bnd = (bfu*)(ws + (42u << 20));   // [1024][C] bf16, 4 MiB
  bfu* y = (bfu*)(ws + (46u << 20));        // [M][C] bf16, 64 MiB

  // 0) x fp32 -> bf16
  cvt_f32_bf16<<<2048, 256, 0, stream>>>(x, xb, M_ * D_ / 8);
  // 1) weight transpose+convert
  transpose_cvt<D_, C_><<<dim3(C_ / 32, D_ / 32), dim3(32, 8), 0, stream>>>(W_exp, wexp_t);
  transpose_cvt<C_, D_><<<dim3(D_ / 32, C_ / 32), dim3(32, 8), 0, stream>>>(W_cmp, wcmp_t);
  // 2) boundary rows: pack 3 preceding x-rows per 256-row tile, then small GEMM.
  bnd_pack<<<189, 128, 0, stream>>>(xb, A_bnd);
  gemm256<1024, C_, D_, true, true><<<32, 512, 0, stream>>>(A_bnd, wexp_t, b_exp, xe_bnd);
  // 3) fused expand GEMM + causal conv -> y
  gemm_exp_conv<<<512, 512, 0, stream>>>(xb, wexp_t, b_exp, cw, cb, xe_bnd, y);
  // 4) compress GEMM: out = y @ W_cmp + b_cmp
  gemm256<M_, D_, C_, false, false><<<256, 512, 0, stream>>>(y, wcmp_t, b_cmp, out);
}